// Round 1
// baseline (186.219 us; speedup 1.0000x reference)
//
#include <hip/hip_runtime.h>
#include <cstdint>
#include <cstddef>

typedef __attribute__((ext_vector_type(8))) __bf16 bf16x8;
typedef __attribute__((ext_vector_type(4))) float f32x4;
typedef __attribute__((ext_vector_type(8))) unsigned short u16x8;

__device__ __forceinline__ unsigned short f2bf(float f) {
  union { float f; unsigned u; } v; v.f = f;
  unsigned u = v.u;
  return (unsigned short)((u + 0x7FFFu + ((u >> 16) & 1u)) >> 16);
}

__device__ __forceinline__ void async16(const void* g, void* l) {
  __builtin_amdgcn_global_load_lds(
      (const __attribute__((address_space(1))) unsigned int*)g,
      (__attribute__((address_space(3))) unsigned int*)l, 16, 0, 0);
}

// ---------------- prologue 1: x fp32 -> bf16 ----------------
__global__ __launch_bounds__(256) void cvt_x_kern(const float* __restrict__ x,
                                                  unsigned short* __restrict__ xb) {
  int idx = blockIdx.x * 256 + threadIdx.x;  // 2,097,152 threads, 8 floats each
  const float4* src = (const float4*)x + (size_t)idx * 2;
  float4 a = src[0], b = src[1];
  u16x8 v;
  v[0] = f2bf(a.x); v[1] = f2bf(a.y); v[2] = f2bf(a.z); v[3] = f2bf(a.w);
  v[4] = f2bf(b.x); v[5] = f2bf(b.y); v[6] = f2bf(b.z); v[7] = f2bf(b.w);
  *((u16x8*)xb + idx) = v;
}

// ---------------- prologue 2: expand W -> M (stored [N][K] bf16) ----------------
// M[n][k] with n = i*64+c, k = j*64+nin, value = W[i][j][(c-nin)&63]
__global__ __launch_bounds__(64) void expand_w_kern(const float* __restrict__ W,
                                                    unsigned short* __restrict__ Mb) {
  int i = blockIdx.x >> 6, j = blockIdx.x & 63;
  int c = threadIdx.x;
  __shared__ unsigned short w16[64];
  w16[c] = f2bf(W[((size_t)(i * 64 + j)) * 64 + c]);
  __syncthreads();
  unsigned short* dst = Mb + (size_t)(i * 64 + c) * 4096 + j * 64;
#pragma unroll
  for (int g = 0; g < 8; ++g) {
    u16x8 v;
#pragma unroll
    for (int e = 0; e < 8; ++e) v[e] = w16[(c - (g * 8 + e)) & 63];
    *(u16x8*)(dst + g * 8) = v;
  }
}

// ---------------- main GEMM: C[M][N] = A[M][K] * B[N][K]^T ----------------
// 128x128 tile, BK=64, 4 waves (2x2), mfma 16x16x32 bf16.
// LDS: As[128 rows][8 slots of 16B], slot XOR-swizzled by (row&7); linear dest for
// global_load_lds, swizzle applied to the per-lane GLOBAL source and to ds_read.
__global__ __launch_bounds__(256) void gemm_bt(const unsigned short* __restrict__ A,
                                               const unsigned short* __restrict__ B,
                                               float* __restrict__ C) {
  __shared__ __align__(16) char lds[32768];
  int bid = blockIdx.x;
  int swz = (bid & 7) * 128 + (bid >> 3);  // bijective: 1024 = 8*128
  int bm = swz >> 5, bn = swz & 31;
  int t = threadIdx.x;
  int w = t >> 6, l = t & 63;
  int wm = (w >> 1) * 64, wn = (w & 1) * 64;

  f32x4 acc[4][4];
#pragma unroll
  for (int a_ = 0; a_ < 4; ++a_)
#pragma unroll
    for (int b_ = 0; b_ < 4; ++b_) acc[a_][b_] = (f32x4){0.f, 0.f, 0.f, 0.f};

  int srow[4], ssl[4];
#pragma unroll
  for (int q = 0; q < 4; ++q) {
    srow[q] = q * 32 + w * 8 + (l >> 3);
    ssl[q] = (l & 7) ^ (srow[q] & 7);  // global k-slot that lands at LDS slot (l&7)
  }
  const size_t abase = (size_t)(bm * 128) * 4096;
  const size_t bbase = (size_t)(bn * 128) * 4096;

  for (int kt = 0; kt < 64; ++kt) {
    __syncthreads();
#pragma unroll
    for (int q = 0; q < 4; ++q) {
      async16(A + abase + (size_t)srow[q] * 4096 + kt * 64 + ssl[q] * 8,
              lds + q * 4096 + w * 1024);
      async16(B + bbase + (size_t)srow[q] * 4096 + kt * 64 + ssl[q] * 8,
              lds + 16384 + q * 4096 + w * 1024);
    }
    __syncthreads();
#pragma unroll
    for (int kh = 0; kh < 2; ++kh) {
      bf16x8 af[4], bfr[4];
#pragma unroll
      for (int mi = 0; mi < 4; ++mi) {
        int row = wm + mi * 16 + (l & 15);
        int sl = (kh * 4 + (l >> 4)) ^ (row & 7);
        af[mi] = *(const bf16x8*)(lds + row * 128 + sl * 16);
      }
#pragma unroll
      for (int ni = 0; ni < 4; ++ni) {
        int row = wn + ni * 16 + (l & 15);
        int sl = (kh * 4 + (l >> 4)) ^ (row & 7);
        bfr[ni] = *(const bf16x8*)(lds + 16384 + row * 128 + sl * 16);
      }
#pragma unroll
      for (int mi = 0; mi < 4; ++mi)
#pragma unroll
        for (int ni = 0; ni < 4; ++ni)
          acc[mi][ni] = __builtin_amdgcn_mfma_f32_16x16x32_bf16(af[mi], bfr[ni],
                                                                acc[mi][ni], 0, 0, 0);
    }
  }

  // C/D layout (m89-verified): col = lane&15, row = (lane>>4)*4 + reg
#pragma unroll
  for (int mi = 0; mi < 4; ++mi) {
    int rbase = bm * 128 + wm + mi * 16 + ((l >> 4) & 3) * 4;
#pragma unroll
    for (int ni = 0; ni < 4; ++ni) {
      int col = bn * 128 + wn + ni * 16 + (l & 15);
#pragma unroll
      for (int r = 0; r < 4; ++r)
        C[(size_t)(rbase + r) * 4096 + col] = acc[mi][ni][r];
    }
  }
}

// ---------------- fallback (no workspace needed): fp32 register-blocked ----------------
__global__ __launch_bounds__(256) void fallback_kern(const float* __restrict__ x,
                                                     const float* __restrict__ W,
                                                     float* __restrict__ out) {
  int bi = blockIdx.x & 63;   // output block i
  int bb = blockIdx.x >> 6;   // batch tile of 64 rows
  int t = threadIdx.x;
  int m = t & 63;             // batch row (lane)
  int cg = t >> 6;            // col group: c = cg*16 + cc
  __shared__ float xs[64][65];
  __shared__ float ws[64];
  float acc[16];
#pragma unroll
  for (int e = 0; e < 16; ++e) acc[e] = 0.f;
  for (int j = 0; j < 64; ++j) {
    __syncthreads();
#pragma unroll
    for (int r = 0; r < 16; ++r) {
      int idx = t + 256 * r;
      int rr = idx >> 6, cc = idx & 63;
      xs[rr][cc] = x[(size_t)(bb * 64 + rr) * 4096 + j * 64 + cc];
    }
    if (t < 64) ws[t] = W[((size_t)(bi * 64 + j)) * 64 + t];
    __syncthreads();
    float xr[64];
#pragma unroll
    for (int e = 0; e < 64; ++e) xr[e] = xs[m][(cg * 16 + e) & 63];
#pragma unroll
    for (int mm = 0; mm < 64; ++mm) {
      float wv = ws[mm];
#pragma unroll
      for (int cc2 = 0; cc2 < 16; ++cc2)
        acc[cc2] = __builtin_fmaf(xr[(cc2 - mm) & 63], wv, acc[cc2]);
    }
  }
  float* dst = out + (size_t)(bb * 64 + m) * 4096 + bi * 64 + cg * 16;
#pragma unroll
  for (int cc2 = 0; cc2 < 16; ++cc2) dst[cc2] = acc[cc2];
}

extern "C" void kernel_launch(void* const* d_in, const int* in_sizes, int n_in,
                              void* d_out, int out_size, void* d_ws, size_t ws_size,
                              hipStream_t stream) {
  const float* x = (const float*)d_in[0];
  const float* W = (const float*)d_in[1];
  float* out = (float*)d_out;
  const size_t need = (size_t)2 * 4096 * 4096 * sizeof(unsigned short);  // 64 MB
  if (ws_size >= need) {
    unsigned short* xb = (unsigned short*)d_ws;
    unsigned short* Mb = xb + (size_t)4096 * 4096;
    cvt_x_kern<<<dim3(8192), dim3(256), 0, stream>>>(x, xb);
    expand_w_kern<<<dim3(4096), dim3(64), 0, stream>>>(W, Mb);
    gemm_bt<<<dim3(1024), dim3(256), 0, stream>>>(xb, Mb, out);
  } else {
    fallback_kern<<<dim3(4096), dim3(256), 0, stream>>>(x, W, out);
  }
}

// Round 2
// 162.304 us; speedup vs baseline: 1.1473x; 1.1473x over previous
//
#include <hip/hip_runtime.h>
#include <cstdint>
#include <cstddef>

typedef __attribute__((ext_vector_type(8))) __bf16 bf16x8;
typedef __attribute__((ext_vector_type(4))) float f32x4;
typedef __attribute__((ext_vector_type(8))) unsigned short u16x8;

__device__ __forceinline__ unsigned short f2bf(float f) {
  union { float f; unsigned u; } v; v.f = f;
  unsigned u = v.u;
  return (unsigned short)((u + 0x7FFFu + ((u >> 16) & 1u)) >> 16);
}

__device__ __forceinline__ void async16(const void* g, void* l) {
  __builtin_amdgcn_global_load_lds(
      (const __attribute__((address_space(1))) unsigned int*)g,
      (__attribute__((address_space(3))) unsigned int*)l, 16, 0, 0);
}

// ---------------- prologue 1: x fp32 -> bf16 ----------------
__global__ __launch_bounds__(256) void cvt_x_kern(const float* __restrict__ x,
                                                  unsigned short* __restrict__ xb) {
  int idx = blockIdx.x * 256 + threadIdx.x;
  const float4* src = (const float4*)x + (size_t)idx * 2;
  float4 a = src[0], b = src[1];
  u16x8 v;
  v[0] = f2bf(a.x); v[1] = f2bf(a.y); v[2] = f2bf(a.z); v[3] = f2bf(a.w);
  v[4] = f2bf(b.x); v[5] = f2bf(b.y); v[6] = f2bf(b.z); v[7] = f2bf(b.w);
  *((u16x8*)xb + idx) = v;
}

// ---------------- prologue 2: expand W -> M (stored [N][K] bf16) ----------------
__global__ __launch_bounds__(64) void expand_w_kern(const float* __restrict__ W,
                                                    unsigned short* __restrict__ Mb) {
  int i = blockIdx.x >> 6, j = blockIdx.x & 63;
  int c = threadIdx.x;
  __shared__ unsigned short w16[64];
  w16[c] = f2bf(W[((size_t)(i * 64 + j)) * 64 + c]);
  __syncthreads();
  unsigned short* dst = Mb + (size_t)(i * 64 + c) * 4096 + j * 64;
#pragma unroll
  for (int g = 0; g < 8; ++g) {
    u16x8 v;
#pragma unroll
    for (int e = 0; e < 8; ++e) v[e] = w16[(c - (g * 8 + e)) & 63];
    *(u16x8*)(dst + g * 8) = v;
  }
}

// ---------------- main GEMM: 256x256 tile, BK=64, 8-phase schedule ----------------
// C[M][N] = A[M][K] * B[N][K]^T. 512 threads = 8 waves (2M x 4N), per-wave 128x64.
// LDS 128 KiB: 2 dbuf x (A[256][64] + B[256][64]) bf16. Linear dest for
// global_load_lds; slot^(row&7) swizzle folded into per-lane GLOBAL source and
// into ds_read addresses (same involution both sides).
template <int QM, int QN, class F>
__device__ __forceinline__ void phase(const char* pa, const char* pb,
                                      const int (&koff)[2], f32x4 (&acc)[8][4],
                                      F&& stagef) {
  bf16x8 af[4][2];
  bf16x8 bfr[2][2];
#pragma unroll
  for (int mi = 0; mi < 4; ++mi)
#pragma unroll
    for (int ks = 0; ks < 2; ++ks)
      af[mi][ks] = *(const bf16x8*)(pa + koff[ks] + (QM * 4 + mi) * 2048);
#pragma unroll
  for (int ni = 0; ni < 2; ++ni)
#pragma unroll
    for (int ks = 0; ks < 2; ++ks)
      bfr[ni][ks] = *(const bf16x8*)(pb + koff[ks] + (QN * 2 + ni) * 2048);
  stagef();
  __builtin_amdgcn_s_barrier();
  asm volatile("s_waitcnt lgkmcnt(0)" ::: "memory");
  __builtin_amdgcn_sched_barrier(0);
  __builtin_amdgcn_s_setprio(1);
#pragma unroll
  for (int ks = 0; ks < 2; ++ks)
#pragma unroll
    for (int mi = 0; mi < 4; ++mi)
#pragma unroll
      for (int ni = 0; ni < 2; ++ni)
        acc[QM * 4 + mi][QN * 2 + ni] = __builtin_amdgcn_mfma_f32_16x16x32_bf16(
            af[mi][ks], bfr[ni][ks], acc[QM * 4 + mi][QN * 2 + ni], 0, 0, 0);
  __builtin_amdgcn_s_setprio(0);
  __builtin_amdgcn_s_barrier();
}

__global__ __launch_bounds__(512, 2) void gemm8(const unsigned short* __restrict__ A,
                                                const unsigned short* __restrict__ B,
                                                float* __restrict__ C) {
  __shared__ __align__(16) char lds[131072];
  int bid = blockIdx.x;
  int swz = (bid & 7) * 32 + (bid >> 3);  // bijective: 256 = 8*32
  int bm = swz >> 4, bn = swz & 15;
  int t = threadIdx.x;
  int w = t >> 6, l = t & 63;
  int wm = (w >> 2) * 128;  // 2 M-groups
  int wn = (w & 3) * 64;    // 4 N-groups

  f32x4 acc[8][4];
#pragma unroll
  for (int a_ = 0; a_ < 8; ++a_)
#pragma unroll
    for (int b_ = 0; b_ < 4; ++b_) acc[a_][b_] = (f32x4){0.f, 0.f, 0.f, 0.f};

  const int rowin = w * 8 + (l >> 3);        // staging row within 64-row group
  const int cslot = (l & 7) ^ (l >> 3);      // pre-swizzled global k-slot
  int koff[2];
#pragma unroll
  for (int ks = 0; ks < 2; ++ks)
    koff[ks] = (l & 15) * 128 + ((ks * 4 + (l >> 4)) ^ (l & 7)) * 16;

  const size_t abase = (size_t)bm * 256 * 4096;
  const size_t bbase = (size_t)bn * 256 * 4096;

  auto stage = [&](int kt, int c) {
    const unsigned short* mat = (c < 2) ? A : B;
    size_t gbase = (c < 2) ? abase : bbase;
    int half = c & 1;
    char* ldst = lds + (kt & 1) * 65536 + ((c < 2) ? 0 : 32768) + half * 16384 + w * 1024;
#pragma unroll
    for (int i = 0; i < 2; ++i) {
      int r = half * 128 + i * 64 + rowin;
      async16(mat + gbase + (size_t)r * 4096 + kt * 64 + cslot * 8, ldst + i * 8192);
    }
  };

  // prologue: tile 0 fully, tile 1 chunks {0,1}
#pragma unroll
  for (int c = 0; c < 4; ++c) stage(0, c);
  stage(1, 0);
  stage(1, 1);
  asm volatile("s_waitcnt vmcnt(4)" ::: "memory");
  __builtin_amdgcn_s_barrier();

  for (int tt = 0; tt < 64; ++tt) {
    int cur = tt & 1;
    const char* pa = lds + cur * 65536 + wm * 128;
    const char* pb = lds + cur * 65536 + 32768 + wn * 128;
    phase<0, 0>(pa, pb, koff, acc, [&] { if (tt < 63) stage(tt + 1, 2); });
    phase<0, 1>(pa, pb, koff, acc, [&] { if (tt < 63) stage(tt + 1, 3); });
    phase<1, 0>(pa, pb, koff, acc, [&] {});
    phase<1, 1>(pa, pb, koff, acc, [&] {});
    if (tt < 63) {
      if (tt < 62) {
        stage(tt + 2, 0);  // into buf[tt&1], released by phase<1,1>'s final barrier
        stage(tt + 2, 1);
        asm volatile("s_waitcnt vmcnt(4)" ::: "memory");  // tile tt+1 fully landed
      } else {
        asm volatile("s_waitcnt vmcnt(0)" ::: "memory");
      }
      __builtin_amdgcn_s_barrier();
    }
  }

  // C/D layout (m89-verified): col = lane&15, row = (lane>>4)*4 + reg
  int r0 = (l >> 4) * 4;
#pragma unroll
  for (int mi = 0; mi < 8; ++mi) {
    size_t row = (size_t)(bm * 256 + wm + mi * 16 + r0);
#pragma unroll
    for (int ni = 0; ni < 4; ++ni) {
      int col = bn * 256 + wn + ni * 16 + (l & 15);
#pragma unroll
      for (int r = 0; r < 4; ++r)
        C[(row + r) * 4096 + col] = acc[mi][ni][r];
    }
  }
}

// ---------------- fallback (no workspace): fp32 register-blocked ----------------
__global__ __launch_bounds__(256) void fallback_kern(const float* __restrict__ x,
                                                     const float* __restrict__ W,
                                                     float* __restrict__ out) {
  int bi = blockIdx.x & 63;
  int bb = blockIdx.x >> 6;
  int t = threadIdx.x;
  int m = t & 63;
  int cg = t >> 6;
  __shared__ float xs[64][65];
  __shared__ float ws[64];
  float acc[16];
#pragma unroll
  for (int e = 0; e < 16; ++e) acc[e] = 0.f;
  for (int j = 0; j < 64; ++j) {
    __syncthreads();
#pragma unroll
    for (int r = 0; r < 16; ++r) {
      int idx = t + 256 * r;
      int rr = idx >> 6, cc = idx & 63;
      xs[rr][cc] = x[(size_t)(bb * 64 + rr) * 4096 + j * 64 + cc];
    }
    if (t < 64) ws[t] = W[((size_t)(bi * 64 + j)) * 64 + t];
    __syncthreads();
    float xr[64];
#pragma unroll
    for (int e = 0; e < 64; ++e) xr[e] = xs[m][(cg * 16 + e) & 63];
#pragma unroll
    for (int mm = 0; mm < 64; ++mm) {
      float wv = ws[mm];
#pragma unroll
      for (int cc2 = 0; cc2 < 16; ++cc2)
        acc[cc2] = __builtin_fmaf(xr[(cc2 - mm) & 63], wv, acc[cc2]);
    }
  }
  float* dst = out + (size_t)(bb * 64 + m) * 4096 + bi * 64 + cg * 16;
#pragma unroll
  for (int cc2 = 0; cc2 < 16; ++cc2) dst[cc2] = acc[cc2];
}

extern "C" void kernel_launch(void* const* d_in, const int* in_sizes, int n_in,
                              void* d_out, int out_size, void* d_ws, size_t ws_size,
                              hipStream_t stream) {
  const float* x = (const float*)d_in[0];
  const float* W = (const float*)d_in[1];
  float* out = (float*)d_out;
  const size_t need = (size_t)2 * 4096 * 4096 * sizeof(unsigned short);  // 64 MB
  if (ws_size >= need) {
    unsigned short* xb = (unsigned short*)d_ws;
    unsigned short* Mb = xb + (size_t)4096 * 4096;
    cvt_x_kern<<<dim3(8192), dim3(256), 0, stream>>>(x, xb);
    expand_w_kern<<<dim3(4096), dim3(64), 0, stream>>>(W, Mb);
    gemm8<<<dim3(256), dim3(512), 0, stream>>>(xb, Mb, out);
  } else {
    fallback_kern<<<dim3(4096), dim3(256), 0, stream>>>(x, W, out);
  }
}

// Round 3
// 145.925 us; speedup vs baseline: 1.2761x; 1.1122x over previous
//
#include <hip/hip_runtime.h>
#include <cstdint>
#include <cstddef>

typedef __attribute__((ext_vector_type(8))) __bf16 bf16x8;
typedef __attribute__((ext_vector_type(4))) float f32x4;
typedef __attribute__((ext_vector_type(8))) unsigned short u16x8;

__device__ __forceinline__ unsigned short f2bf(float f) {
  union { float f; unsigned u; } v; v.f = f;
  unsigned u = v.u;
  return (unsigned short)((u + 0x7FFFu + ((u >> 16) & 1u)) >> 16);
}

__device__ __forceinline__ void async16(const void* g, void* l) {
  __builtin_amdgcn_global_load_lds(
      (const __attribute__((address_space(1))) unsigned int*)g,
      (__attribute__((address_space(3))) unsigned int*)l, 16, 0, 0);
}

// ---------------- prologue 1: x fp32 -> bf16 ----------------
__global__ __launch_bounds__(256) void cvt_x_kern(const float* __restrict__ x,
                                                  unsigned short* __restrict__ xb) {
  int idx = blockIdx.x * 256 + threadIdx.x;
  const float4* src = (const float4*)x + (size_t)idx * 2;
  float4 a = src[0], b = src[1];
  u16x8 v;
  v[0] = f2bf(a.x); v[1] = f2bf(a.y); v[2] = f2bf(a.z); v[3] = f2bf(a.w);
  v[4] = f2bf(b.x); v[5] = f2bf(b.y); v[6] = f2bf(b.z); v[7] = f2bf(b.w);
  *((u16x8*)xb + idx) = v;
}

// ---------------- prologue 2: expand W -> M (stored [N][K] bf16) ----------------
__global__ __launch_bounds__(64) void expand_w_kern(const float* __restrict__ W,
                                                    unsigned short* __restrict__ Mb) {
  int i = blockIdx.x >> 6, j = blockIdx.x & 63;
  int c = threadIdx.x;
  __shared__ unsigned short w16[64];
  w16[c] = f2bf(W[((size_t)(i * 64 + j)) * 64 + c]);
  __syncthreads();
  unsigned short* dst = Mb + (size_t)(i * 64 + c) * 4096 + j * 64;
#pragma unroll
  for (int g = 0; g < 8; ++g) {
    u16x8 v;
#pragma unroll
    for (int e = 0; e < 8; ++e) v[e] = w16[(c - (g * 8 + e)) & 63];
    *(u16x8*)(dst + g * 8) = v;
  }
}

// ---------------- main GEMM: 256x256 tile, BK=64, 4-phase Gray-code schedule ----------------
// C[M][N] = A[M][K] * B[N][K]^T. 512 threads = 8 waves (2M x 4N), per-wave 128x64.
// Each fragment is read from LDS exactly ONCE per K-tile (24 b128/wave/tile):
//   P0: A-low(8) + B-low(4) -> MFMA quad (0,0)
//   P1: B-high(4)           -> MFMA quad (0,1)
//   P2: A-high(8)           -> MFMA quad (1,1)
//   P3: no reads, stage t+2 -> MFMA quad (1,0)
// LDS 128 KiB: 2 dbuf x (A[256][64] + B[256][64]) bf16, slot^(row&7) swizzle
// folded into per-lane global source and ds_read addresses (both-sides involution).
__global__ __launch_bounds__(512, 2) void gemm8(const unsigned short* __restrict__ A,
                                                const unsigned short* __restrict__ B,
                                                float* __restrict__ C) {
  __shared__ __align__(16) char lds[131072];
  int bid = blockIdx.x;
  int swz = (bid & 7) * 32 + (bid >> 3);  // bijective: 256 = 8*32
  int bm = swz >> 4, bn = swz & 15;
  int t = threadIdx.x;
  int w = t >> 6, l = t & 63;
  int wm = (w >> 2) * 128;  // 2 M-groups
  int wn = (w & 3) * 64;    // 4 N-groups

  f32x4 acc[8][4];
#pragma unroll
  for (int a_ = 0; a_ < 8; ++a_)
#pragma unroll
    for (int b_ = 0; b_ < 4; ++b_) acc[a_][b_] = (f32x4){0.f, 0.f, 0.f, 0.f};

  const int rowin = w * 8 + (l >> 3);    // staging row within 64-row group
  const int cslot = (l & 7) ^ (l >> 3);  // pre-swizzled global k-slot
  int koff[2];
#pragma unroll
  for (int ks = 0; ks < 2; ++ks)
    koff[ks] = (l & 15) * 128 + ((ks * 4 + (l >> 4)) ^ (l & 7)) * 16;

  const size_t abase = (size_t)bm * 256 * 4096;
  const size_t bbase = (size_t)bn * 256 * 4096;

  auto stage = [&](int kt, int c) {
    const unsigned short* mat = (c < 2) ? A : B;
    size_t gbase = (c < 2) ? abase : bbase;
    int half = c & 1;
    char* ldst = lds + (kt & 1) * 65536 + ((c < 2) ? 0 : 32768) + half * 16384 + w * 1024;
#pragma unroll
    for (int i = 0; i < 2; ++i) {
      int r = half * 128 + i * 64 + rowin;
      async16(mat + gbase + (size_t)r * 4096 + kt * 64 + cslot * 8, ldst + i * 8192);
    }
  };

#define MFMA_QUAD(AF, MBASE, BF, NBASE)                                          \
  __builtin_amdgcn_s_setprio(1);                                                 \
  _Pragma("unroll") for (int ks = 0; ks < 2; ++ks)                               \
      _Pragma("unroll") for (int mi = 0; mi < 4; ++mi)                           \
      _Pragma("unroll") for (int ni = 0; ni < 2; ++ni)                           \
      acc[(MBASE) + mi][(NBASE) + ni] = __builtin_amdgcn_mfma_f32_16x16x32_bf16( \
          AF[mi][ks], BF[(NBASE) + ni][ks], acc[(MBASE) + mi][(NBASE) + ni], 0,  \
          0, 0);                                                                 \
  __builtin_amdgcn_s_setprio(0);

  // prologue: tile 0 fully, tile 1 chunks {0,1}
#pragma unroll
  for (int c = 0; c < 4; ++c) stage(0, c);
  stage(1, 0);
  stage(1, 1);
  asm volatile("s_waitcnt vmcnt(4)" ::: "memory");
  __builtin_amdgcn_s_barrier();

  for (int tt = 0; tt < 64; ++tt) {
    int cur = tt & 1;
    const char* pa = lds + cur * 65536 + wm * 128;
    const char* pb = lds + cur * 65536 + 32768 + wn * 128;
    bf16x8 a0[4][2], a1[4][2], bf[4][2];

    // ---- P0: read A-low + B-low, stage (tt+1, B-half0), MFMA (0,0) ----
#pragma unroll
    for (int mi = 0; mi < 4; ++mi)
#pragma unroll
      for (int ks = 0; ks < 2; ++ks)
        a0[mi][ks] = *(const bf16x8*)(pa + koff[ks] + mi * 2048);
#pragma unroll
    for (int ni = 0; ni < 2; ++ni)
#pragma unroll
      for (int ks = 0; ks < 2; ++ks)
        bf[ni][ks] = *(const bf16x8*)(pb + koff[ks] + ni * 2048);
    if (tt < 63) stage(tt + 1, 2);
    __builtin_amdgcn_s_barrier();
    asm volatile("s_waitcnt lgkmcnt(0)" ::: "memory");
    __builtin_amdgcn_sched_barrier(0);
    MFMA_QUAD(a0, 0, bf, 0)
    __builtin_amdgcn_s_barrier();

    // ---- P1: read B-high, stage (tt+1, B-half1), MFMA (0,1) ----
#pragma unroll
    for (int ni = 2; ni < 4; ++ni)
#pragma unroll
      for (int ks = 0; ks < 2; ++ks)
        bf[ni][ks] = *(const bf16x8*)(pb + koff[ks] + ni * 2048);
    if (tt < 63) stage(tt + 1, 3);
    __builtin_amdgcn_s_barrier();
    asm volatile("s_waitcnt lgkmcnt(0)" ::: "memory");
    __builtin_amdgcn_sched_barrier(0);
    MFMA_QUAD(a0, 0, bf, 2)
    __builtin_amdgcn_s_barrier();

    // ---- P2: read A-high, MFMA (1,1) ----
#pragma unroll
    for (int mi = 0; mi < 4; ++mi)
#pragma unroll
      for (int ks = 0; ks < 2; ++ks)
        a1[mi][ks] = *(const bf16x8*)(pa + koff[ks] + (4 + mi) * 2048);
    __builtin_amdgcn_s_barrier();
    asm volatile("s_waitcnt lgkmcnt(0)" ::: "memory");
    __builtin_amdgcn_sched_barrier(0);
    MFMA_QUAD(a1, 4, bf, 2)
    __builtin_amdgcn_s_barrier();

    // ---- P3: no reads; stage (tt+2, A-halves); MFMA (1,0) ----
    // Safe: all buf[cur] A-reads were drained by P2's lgkmcnt(0) before its
    // trailing barrier, so overwriting buf[cur]'s A region here races nothing.
    if (tt < 62) {
      stage(tt + 2, 0);
      stage(tt + 2, 1);
    }
    __builtin_amdgcn_s_barrier();
    MFMA_QUAD(a1, 4, bf, 0)
    __builtin_amdgcn_s_barrier();

    // ---- tile boundary: tile tt+1 must be fully landed ----
    if (tt < 63) {
      if (tt < 62)
        asm volatile("s_waitcnt vmcnt(4)" ::: "memory");
      else
        asm volatile("s_waitcnt vmcnt(0)" ::: "memory");
      __builtin_amdgcn_s_barrier();
    }
  }
#undef MFMA_QUAD

  // C/D layout (m89-verified): col = lane&15, row = (lane>>4)*4 + reg
  int r0 = (l >> 4) * 4;
#pragma unroll
  for (int mi = 0; mi < 8; ++mi) {
    size_t row = (size_t)(bm * 256 + wm + mi * 16 + r0);
#pragma unroll
    for (int ni = 0; ni < 4; ++ni) {
      int col = bn * 256 + wn + ni * 16 + (l & 15);
#pragma unroll
      for (int r = 0; r < 4; ++r)
        C[(row + r) * 4096 + col] = acc[mi][ni][r];
    }
  }
}

// ---------------- fallback (no workspace): fp32 register-blocked ----------------
__global__ __launch_bounds__(256) void fallback_kern(const float* __restrict__ x,
                                                     const float* __restrict__ W,
                                                     float* __restrict__ out) {
  int bi = blockIdx.x & 63;
  int bb = blockIdx.x >> 6;
  int t = threadIdx.x;
  int m = t & 63;
  int cg = t >> 6;
  __shared__ float xs[64][65];
  __shared__ float ws[64];
  float acc[16];
#pragma unroll
  for (int e = 0; e < 16; ++e) acc[e] = 0.f;
  for (int j = 0; j < 64; ++j) {
    __syncthreads();
#pragma unroll
    for (int r = 0; r < 16; ++r) {
      int idx = t + 256 * r;
      int rr = idx >> 6, cc = idx & 63;
      xs[rr][cc] = x[(size_t)(bb * 64 + rr) * 4096 + j * 64 + cc];
    }
    if (t < 64) ws[t] = W[((size_t)(bi * 64 + j)) * 64 + t];
    __syncthreads();
    float xr[64];
#pragma unroll
    for (int e = 0; e < 64; ++e) xr[e] = xs[m][(cg * 16 + e) & 63];
#pragma unroll
    for (int mm = 0; mm < 64; ++mm) {
      float wv = ws[mm];
#pragma unroll
      for (int cc2 = 0; cc2 < 16; ++cc2)
        acc[cc2] = __builtin_fmaf(xr[(cc2 - mm) & 63], wv, acc[cc2]);
    }
  }
  float* dst = out + (size_t)(bb * 64 + m) * 4096 + bi * 64 + cg * 16;
#pragma unroll
  for (int cc2 = 0; cc2 < 16; ++cc2) dst[cc2] = acc[cc2];
}

extern "C" void kernel_launch(void* const* d_in, const int* in_sizes, int n_in,
                              void* d_out, int out_size, void* d_ws, size_t ws_size,
                              hipStream_t stream) {
  const float* x = (const float*)d_in[0];
  const float* W = (const float*)d_in[1];
  float* out = (float*)d_out;
  const size_t need = (size_t)2 * 4096 * 4096 * sizeof(unsigned short);  // 64 MB
  if (ws_size >= need) {
    unsigned short* xb = (unsigned short*)d_ws;
    unsigned short* Mb = xb + (size_t)4096 * 4096;
    cvt_x_kern<<<dim3(8192), dim3(256), 0, stream>>>(x, xb);
    expand_w_kern<<<dim3(4096), dim3(64), 0, stream>>>(W, Mb);
    gemm8<<<dim3(256), dim3(512), 0, stream>>>(xb, Mb, out);
  } else {
    fallback_kern<<<dim3(4096), dim3(256), 0, stream>>>(x, W, out);
  }
}